// Round 6
// baseline (3462.440 us; speedup 1.0000x reference)
//
#include <hip/hip_runtime.h>
#include <stdint.h>

typedef __bf16 v8bf __attribute__((ext_vector_type(8)));
typedef float v4f __attribute__((ext_vector_type(4)));
typedef unsigned short u16;
typedef unsigned long long u64;

constexpr int kB = 256, kT = 128, kI = 512, kH = 1024, kO = 32;
constexpr int kBlocks = 256, kThreads = 256;
constexpr int KSX = kI / 32;   // 16 k-slices of 32 in x
constexpr int KSH = kH / 32;   // 32 k-slices of 32 in h
constexpr int QX = KSX / 4;    // 4  x-slices per wave (k-split)
constexpr int QH = KSH / 4;    // 8  h-slices per wave

// workspace layout (bytes)
constexpr size_t OFF_FLG = 0;                                   // flags[4][64], 16B stride
constexpr size_t OFF_H   = 8192;                                // 2 x 512KB frag-layout h
constexpr size_t SZ_H    = (size_t)2 * kB * kH * 2;
constexpr size_t OFF_XT  = OFF_H + SZ_H;                        // frag-tiled x (bf16)
constexpr size_t SZ_XT   = (size_t)kB * kT * kI * 2;            // 32 MB
constexpr size_t OFF_WIT = OFF_XT + SZ_XT;                      // 4 x 1MB wi frag tiles
constexpr size_t SZ_WIT  = (size_t)kH * kI * 2;
constexpr size_t OFF_WHT = OFF_WIT + 4 * SZ_WIT;                // 4 x 2MB wh frag tiles
constexpr size_t SZ_WHT  = (size_t)kH * kH * 2;

struct LstmParams {
  const u16* xt;        // frag-tiled x: [t][mt][mi][ks(16)][lane][8]
  const u16* wit[4];    // frag-tiled wi: [ut][ks(16)][lane][8], gates i,f,g,o
  const u16* wht[4];    // frag-tiled wh: [ut][ks(32)][lane][8]
  const float* bi[4];
  const float* bh[4];
  const float* wfc;     // fp32 [O][H]
  float* out;           // fp32 [B][O]
  unsigned* flags;      // [4][64], 16B stride
  u16* hbuf;            // 2 x frag-layout h: [mt][mi][ks(32)][lane][8]
};

static __device__ __forceinline__ float b2f(u16 v) {
  union { float f; uint32_t i; } u; u.i = ((uint32_t)v) << 16; return u.f;
}
static __device__ __forceinline__ u16 f2b(float f) {
  union { float f; uint32_t i; } u; u.f = f;
  return (u16)((u.i + 0x7fffu + ((u.i >> 16) & 1u)) >> 16);
}
static __device__ __forceinline__ float sigm(float x) { return 1.f / (1.f + __expf(-x)); }
static __device__ __forceinline__ float tanh_f(float x) {
  float e = __expf(2.f * x);
  return 1.f - 2.f / (e + 1.f);
}

// ---- prepass: fp32 -> bf16 frag-tiling -------------------------------------
// x[m][t][k] -> xt frag order [t][mt][mi][ks][lane][8]
__global__ __launch_bounds__(256) void cvt_x_tile(const float* __restrict__ x,
                                                  u16* __restrict__ xt) {
  const int gid = blockIdx.x * 256 + threadIdx.x;    // 2^21 threads exactly
  const int lane = gid & 63;
  const int ks = (gid >> 6) & 15;
  const int mi = (gid >> 10) & 3;
  const int mt = (gid >> 12) & 3;
  const int t  = gid >> 14;
  const int m = mt * 64 + mi * 16 + (lane & 15);
  const int k = ks * 32 + (lane >> 4) * 8;
  const float4* s = (const float4*)(x + ((size_t)m * kT + t) * kI + k);
  const float4 a = s[0], b = s[1];
  uint4 o = {f2b(a.x) | ((uint32_t)f2b(a.y) << 16), f2b(a.z) | ((uint32_t)f2b(a.w) << 16),
             f2b(b.x) | ((uint32_t)f2b(b.y) << 16), f2b(b.z) | ((uint32_t)f2b(b.w) << 16)};
  *(uint4*)(xt + (size_t)gid * 8) = o;
}

// W[u][k] (row-major, K=512 or 1024) -> frag order [ut][ks][lane][8]
__global__ __launch_bounds__(256) void cvt_w_tile(const float* __restrict__ w,
                                                  u16* __restrict__ wt,
                                                  int K, int lgKS) {
  const int gid = blockIdx.x * 256 + threadIdx.x;
  const int lane = gid & 63;
  const int rest = gid >> 6;
  const int ks = rest & ((1 << lgKS) - 1);
  const int ut2 = rest >> lgKS;
  const int u = ut2 * 16 + (lane & 15);
  const int k = ks * 32 + (lane >> 4) * 8;
  const float4* s = (const float4*)(w + (size_t)u * K + k);
  const float4 a = s[0], b = s[1];
  uint4 o = {f2b(a.x) | ((uint32_t)f2b(a.y) << 16), f2b(a.z) | ((uint32_t)f2b(a.w) << 16),
             f2b(b.x) | ((uint32_t)f2b(b.y) << 16), f2b(b.z) | ((uint32_t)f2b(b.w) << 16)};
  *(uint4*)(wt + (size_t)gid * 8) = o;
}

// ---- persistent recurrence kernel ------------------------------------------
// __launch_bounds__(256,2): hard-cap 256 VGPR/wave — keeps us inside the
// r2-r4-proven cooperative-launch envelope (r5's ~400-VGPR build was rejected
// by the coop occupancy check and silently never launched).
__global__ __launch_bounds__(kThreads, 2) void lstm_kernel(LstmParams p) {
  // 64 KB: reduction buffer during the loop; FC staging after it.
  __shared__ __align__(16) char smem[64 * 64 * 16];
  v4f* Red = (v4f*)smem;              // [slot = wvp*16+g*4+m][lane]
  u16* shFC = (u16*)smem;             // 8 rows x 1024 bf16 (post-loop only)

  const int tid = threadIdx.x;
  const int lane = tid & 63;
  const int wv = tid >> 6;           // wave = K-quarter owner AND m-tile owner in combine
  const int blk = blockIdx.x;
  const int mt = blk & 3;            // batch tile 0..3 = barrier group
  const int ut = blk >> 2;           // 0..63: 16 hidden units (x4 gates)

  const int mloc = lane & 15;
  const int q = lane >> 4;
  const int uglob = ut * 16 + mloc;

  unsigned* gflags = p.flags + mt * 256;   // 64 slots, stride 4 u32 (16B)

  float bias[4];
#pragma unroll
  for (int g = 0; g < 4; ++g) bias[g] = p.bi[g][uglob] + p.bh[g][uglob];

  float creg[4] = {0.f, 0.f, 0.f, 0.f};    // cell state for rows mt*64+wv*16+q*4+r

  // ---- h-weights resident in registers (128 VGPRs); x-weights streamed ----
  v8bf bhh[QH][4];
#pragma unroll
  for (int g = 0; g < 4; ++g)
#pragma unroll
    for (int i = 0; i < QH; ++i)
      bhh[i][g] = *((const v8bf*)p.wht[g] + ((size_t)(ut * KSH + wv * QH + i) * 64 + lane));

  for (int t = 0; t < kT; ++t) {
    v4f acc[4][4];    // [m-tile][gate] partials for this wave's K-quarter
#pragma unroll
    for (int m = 0; m < 4; ++m)
#pragma unroll
      for (int g = 0; g < 4; ++g) acc[m][g] = (v4f){0.f, 0.f, 0.f, 0.f};

    // ---- phase X: x-part MFMAs, pre-poll (independent of h); bx from L2 ----
    const v8bf* xf = (const v8bf*)p.xt + ((size_t)(t * 4 + mt) * 4 * KSX) * 64;
#pragma unroll
    for (int i = 0; i < QX; ++i) {
      v8bf bxl[4];
#pragma unroll
      for (int g = 0; g < 4; ++g)
        bxl[g] = *((const v8bf*)p.wit[g] + ((size_t)(ut * KSX + wv * QX + i) * 64 + lane));
#pragma unroll
      for (int mi = 0; mi < 4; ++mi) {
        const v8bf a = xf[(size_t)(mi * KSX + wv * QX + i) * 64 + lane];
#pragma unroll
        for (int g = 0; g < 4; ++g)
          acc[mi][g] = __builtin_amdgcn_mfma_f32_16x16x32_bf16(a, bxl[g], acc[mi][g], 0, 0, 0);
      }
    }

    if (t > 0) {
      if (wv == 0) {   // group barrier: 64 lanes poll 64 padded flags
        while (true) {
          unsigned v = __hip_atomic_load(&gflags[lane * 4], __ATOMIC_RELAXED,
                                         __HIP_MEMORY_SCOPE_AGENT);
          if (__ballot(v >= (unsigned)t) == ~0ull) break;
          __builtin_amdgcn_s_sleep(1);
        }
      }
      __syncthreads();

      // ---- phase H: h frags direct LLC->VGPR (relaxed agent loads) ----
      u64* hf = (u64*)(p.hbuf + (size_t)(t & 1) * kB * kH);
#pragma unroll
      for (int mi = 0; mi < 4; ++mi)
#pragma unroll
        for (int i = 0; i < QH; ++i) {
          const size_t fi = ((size_t)((mt * 4 + mi) * KSH + wv * QH + i) * 64 + lane) * 2;
          union { u64 qd[2]; v8bf v; } A;
          A.qd[0] = __hip_atomic_load(hf + fi, __ATOMIC_RELAXED, __HIP_MEMORY_SCOPE_AGENT);
          A.qd[1] = __hip_atomic_load(hf + fi + 1, __ATOMIC_RELAXED, __HIP_MEMORY_SCOPE_AGENT);
#pragma unroll
          for (int g = 0; g < 4; ++g)
            acc[mi][g] = __builtin_amdgcn_mfma_f32_16x16x32_bf16(A.v, bhh[i][g], acc[mi][g], 0, 0, 0);
        }
    }

    // ---- cross-wave K-reduction through LDS ----
#pragma unroll
    for (int m = 0; m < 4; ++m)
#pragma unroll
      for (int g = 0; g < 4; ++g)
        Red[(wv * 16 + g * 4 + m) * 64 + lane] = acc[m][g];
    __syncthreads();

    // combine: this thread owns rows mt*64+wv*16+q*4+{0..3}, unit uglob
    v4f gacc[4];
#pragma unroll
    for (int g = 0; g < 4; ++g) {
      v4f s = Red[(0 * 16 + g * 4 + wv) * 64 + lane];
#pragma unroll
      for (int wvp = 1; wvp < 4; ++wvp) {
        const v4f z = Red[(wvp * 16 + g * 4 + wv) * 64 + lane];
#pragma unroll
        for (int r = 0; r < 4; ++r) s[r] += z[r];
      }
      gacc[g] = s;
    }

    u16* hw = p.hbuf + (size_t)((t + 1) & 1) * kB * kH;
    const int ks_u = uglob >> 5;
    const int hi_u = (uglob >> 3) & 3;
    const int j_u = uglob & 7;
#pragma unroll
    for (int r = 0; r < 4; ++r) {
      const float iv = sigm(gacc[0][r] + bias[0]);
      const float fv = sigm(gacc[1][r] + bias[1]);
      const float gv = tanh_f(gacc[2][r] + bias[2]);
      const float ov = sigm(gacc[3][r] + bias[3]);
      creg[r] = fv * creg[r] + iv * gv;
      const float hv = ov * tanh_f(creg[r]);
      // frag-layout h store: row16 = q*4+r, lane' = row16 | (hi_u<<4)
      const int L = (q * 4 + r) | (hi_u << 4);
      const size_t off = ((size_t)((mt * 4 + wv) * KSH + ks_u) * 64 + L) * 8 + j_u;
      __hip_atomic_store(hw + off, f2b(hv), __ATOMIC_RELAXED, __HIP_MEMORY_SCOPE_AGENT);
    }

    __syncthreads();   // drains vmcnt: all h stores acked at LLC (r4-validated mechanism)
    if (tid == 0)
      __hip_atomic_fetch_add(&gflags[ut * 4], 1u, __ATOMIC_RELAXED,
                             __HIP_MEMORY_SCOPE_AGENT);
  }

  // ---- FC + log_softmax: blocks 0..31, 8 rows x 32 cols. h_last in buf 0 ----
  if (blk < 32) {
    const int gg = blk >> 3;   // mt of rows blk*8..+8
    if (wv == 0) {
      while (true) {
        unsigned v = __hip_atomic_load(&p.flags[gg * 256 + lane * 4], __ATOMIC_RELAXED,
                                       __HIP_MEMORY_SCOPE_AGENT);
        if (__ballot(v >= (unsigned)kT) == ~0ull) break;
        __builtin_amdgcn_s_sleep(1);
      }
    }
    __syncthreads();
    // stage 8 rows from frag-layout h into shFC[row][u]
    {
      const int mi = (blk >> 1) & 3;
      const int ks2 = tid >> 3;        // 0..31
      const int ug = (tid >> 1) & 3;   // unit 8-group
      const int rh = tid & 1;          // row half
      u64* hf = (u64*)p.hbuf;          // buffer 0 (kT even)
#pragma unroll
      for (int rr = 0; rr < 4; ++rr) {
        const int row_l = rh * 4 + rr;
        const int r16 = (blk & 1) * 8 + row_l;
        const int L = r16 | (ug << 4);
        const size_t fi = ((size_t)((gg * 4 + mi) * KSH + ks2) * 64 + L) * 2;
        const u64 a = __hip_atomic_load(hf + fi, __ATOMIC_RELAXED, __HIP_MEMORY_SCOPE_AGENT);
        const u64 b = __hip_atomic_load(hf + fi + 1, __ATOMIC_RELAXED, __HIP_MEMORY_SCOPE_AGENT);
        u64* d = (u64*)&shFC[row_l * kH + ks2 * 32 + ug * 8];
        d[0] = a; d[1] = b;
      }
    }
    __syncthreads();
    const int row = tid >> 5;
    const int col = tid & 31;
    const u16* hr = &shFC[row * kH];
    const float* wr = p.wfc + (size_t)col * kH;
    float s = 0.f;
    for (int k = 0; k < kH; k += 4) {
      const float4 w4 = *(const float4*)(wr + k);
      s += b2f(hr[k]) * w4.x + b2f(hr[k + 1]) * w4.y +
           b2f(hr[k + 2]) * w4.z + b2f(hr[k + 3]) * w4.w;
    }
    float mx = s;
#pragma unroll
    for (int off = 16; off; off >>= 1) mx = fmaxf(mx, __shfl_xor(mx, off, 32));
    const float ex = __expf(s - mx);
    float se = ex;
#pragma unroll
    for (int off = 16; off; off >>= 1) se += __shfl_xor(se, off, 32);
    p.out[(blk * 8 + row) * kO + col] = s - mx - __logf(se);
  }
}

extern "C" void kernel_launch(void* const* d_in, const int* in_sizes, int n_in,
                              void* d_out, int out_size, void* d_ws, size_t ws_size,
                              hipStream_t stream) {
  (void)in_sizes; (void)n_in; (void)out_size; (void)ws_size;
  char* ws = (char*)d_ws;

  u16* xt = (u16*)(ws + OFF_XT);
  u16 *wit[4], *wht[4];
  for (int g = 0; g < 4; ++g) {
    wit[g] = (u16*)(ws + OFF_WIT + (size_t)g * SZ_WIT);
    wht[g] = (u16*)(ws + OFF_WHT + (size_t)g * SZ_WHT);
  }

  // dict order: x, (w_ii,w_hi,b_ii,b_hi), (w_if,w_hf,b_if,b_hf),
  //             (w_io,w_ho,b_io,b_ho), (w_ic,w_hc,b_ic,b_hc), w_fc
  // gate order: 0=i, 1=f, 2=g(candidate), 3=o
  const int gsrc[4] = {1, 5, 13, 9};

  hipMemsetAsync(d_ws, 0, 8192, stream);   // zero barrier flags

  cvt_x_tile<<<8192, 256, 0, stream>>>((const float*)d_in[0], xt);
  for (int g = 0; g < 4; ++g) {
    cvt_w_tile<<<256, 256, 0, stream>>>((const float*)d_in[gsrc[g]], wit[g], kI, 4);
    cvt_w_tile<<<512, 256, 0, stream>>>((const float*)d_in[gsrc[g] + 1], wht[g], kH, 5);
  }

  LstmParams p;
  p.xt = xt;
  for (int g = 0; g < 4; ++g) {
    p.wit[g] = wit[g];
    p.wht[g] = wht[g];
    p.bi[g] = (const float*)d_in[gsrc[g] + 2];
    p.bh[g] = (const float*)d_in[gsrc[g] + 3];
  }
  p.wfc = (const float*)d_in[17];
  p.out = (float*)d_out;
  p.flags = (unsigned*)(ws + OFF_FLG);
  p.hbuf = (u16*)(ws + OFF_H);

  void* args[] = {&p};
  hipError_t e = hipLaunchCooperativeKernel((void*)lstm_kernel, dim3(kBlocks),
                                            dim3(kThreads), args, 0, stream);
  if (e != hipSuccess) {
    // Never fail silently again (r5 lesson). At <=256 VGPR + 64 KB LDS the
    // device holds >=1 block/CU, so a 256-block plain launch co-schedules all
    // blocks and the spin barriers remain safe.
    (void)hipGetLastError();   // clear sticky error
    lstm_kernel<<<dim3(kBlocks), dim3(kThreads), 0, stream>>>(p);
  }
}

// Round 8
// 1487.432 us; speedup vs baseline: 2.3278x; 2.3278x over previous
//
#include <hip/hip_runtime.h>
#include <stdint.h>

#define GAS __attribute__((address_space(1)))
#define LAS __attribute__((address_space(3)))

typedef __bf16 v8bf __attribute__((ext_vector_type(8)));
typedef float v4f __attribute__((ext_vector_type(4)));
typedef unsigned short u16;
typedef unsigned long long u64;

constexpr int kB = 256, kT = 128, kI = 512, kH = 1024, kO = 32;
constexpr int kBlocks = 256, kThreads = 256;
constexpr int KSX = kI / 32;   // 16 k-slices of 32 in x
constexpr int KSH = kH / 32;   // 32 k-slices of 32 in h
constexpr int QX = KSX / 4;    // 4  x-slices per wave (k-split)
constexpr int QH = KSH / 4;    // 8  h-slices per wave

// workspace layout (bytes)
constexpr size_t OFF_FLG = 0;                                   // flags[4][64], 16B stride
constexpr size_t OFF_H   = 8192;                                // 2 x 512KB frag-layout h
constexpr size_t SZ_H    = (size_t)2 * kB * kH * 2;
constexpr size_t OFF_XT  = OFF_H + SZ_H;                        // frag-tiled x (bf16)
constexpr size_t SZ_XT   = (size_t)kB * kT * kI * 2;            // 32 MB
constexpr size_t OFF_WIT = OFF_XT + SZ_XT;                      // 4 x 1MB wi frag tiles
constexpr size_t SZ_WIT  = (size_t)kH * kI * 2;
constexpr size_t OFF_WHT = OFF_WIT + 4 * SZ_WIT;                // 4 x 2MB wh frag tiles
constexpr size_t SZ_WHT  = (size_t)kH * kH * 2;

struct LstmParams {
  const u16* xt;        // frag-tiled x: [t][mt][mi][ks(16)][lane][8]
  const u16* wit[4];    // frag-tiled wi: [ut][ks(16)][lane][8], gates i,f,g,o
  const u16* wht[4];    // frag-tiled wh: [ut][ks(32)][lane][8]
  const float* bi[4];
  const float* bh[4];
  const float* wfc;     // fp32 [O][H]
  float* out;           // fp32 [B][O]
  unsigned* flags;      // [4][64], 16B stride
  u16* hbuf;            // 2 x frag-layout h: [mt][mi][ks(32)][lane][8]
};

static __device__ __forceinline__ float b2f(u16 v) {
  union { float f; uint32_t i; } u; u.i = ((uint32_t)v) << 16; return u.f;
}
static __device__ __forceinline__ u16 f2b(float f) {
  union { float f; uint32_t i; } u; u.f = f;
  return (u16)((u.i + 0x7fffu + ((u.i >> 16) & 1u)) >> 16);
}
static __device__ __forceinline__ float sigm(float x) { return 1.f / (1.f + __expf(-x)); }
static __device__ __forceinline__ float tanh_f(float x) {
  float e = __expf(2.f * x);
  return 1.f - 2.f / (e + 1.f);
}
// coherent async global->LDS, 16B/lane, sc0|sc1 (bypass L1/L2, LLC-serviced).
// r2-r4 PROVEN fast coherent-read path (atomic data loads blew FETCH 6x in r6).
// RULE (r7 lesson): a vmcnt(0) wait (e.g. __syncthreads) MUST sit between the
// issue and any ds_read of the destination — the compiler cannot see the
// LDS dependency through the AS(3) pointer and will NOT insert the wait.
static __device__ __forceinline__ void ld16c(const void* g, void* l) {
  __builtin_amdgcn_global_load_lds((const GAS uint32_t*)g, (LAS uint32_t*)l, 16, 0, 0x11);
}

// ---- prepass: fp32 -> bf16 frag-tiling -------------------------------------
// x[m][t][k] -> xt frag order [t][mt][mi][ks][lane][8]
__global__ __launch_bounds__(256) void cvt_x_tile(const float* __restrict__ x,
                                                  u16* __restrict__ xt) {
  const int gid = blockIdx.x * 256 + threadIdx.x;    // 2^21 threads exactly
  const int lane = gid & 63;
  const int ks = (gid >> 6) & 15;
  const int mi = (gid >> 10) & 3;
  const int mt = (gid >> 12) & 3;
  const int t  = gid >> 14;
  const int m = mt * 64 + mi * 16 + (lane & 15);
  const int k = ks * 32 + (lane >> 4) * 8;
  const float4* s = (const float4*)(x + ((size_t)m * kT + t) * kI + k);
  const float4 a = s[0], b = s[1];
  uint4 o = {f2b(a.x) | ((uint32_t)f2b(a.y) << 16), f2b(a.z) | ((uint32_t)f2b(a.w) << 16),
             f2b(b.x) | ((uint32_t)f2b(b.y) << 16), f2b(b.z) | ((uint32_t)f2b(b.w) << 16)};
  *(uint4*)(xt + (size_t)gid * 8) = o;
}

// W[u][k] (row-major, K=512 or 1024) -> frag order [ut][ks][lane][8]
__global__ __launch_bounds__(256) void cvt_w_tile(const float* __restrict__ w,
                                                  u16* __restrict__ wt,
                                                  int K, int lgKS) {
  const int gid = blockIdx.x * 256 + threadIdx.x;
  const int lane = gid & 63;
  const int rest = gid >> 6;
  const int ks = rest & ((1 << lgKS) - 1);
  const int ut2 = rest >> lgKS;
  const int u = ut2 * 16 + (lane & 15);
  const int k = ks * 32 + (lane >> 4) * 8;
  const float4* s = (const float4*)(w + (size_t)u * K + k);
  const float4 a = s[0], b = s[1];
  uint4 o = {f2b(a.x) | ((uint32_t)f2b(a.y) << 16), f2b(a.z) | ((uint32_t)f2b(a.w) << 16),
             f2b(b.x) | ((uint32_t)f2b(b.y) << 16), f2b(b.z) | ((uint32_t)f2b(b.w) << 16)};
  *(uint4*)(wt + (size_t)gid * 8) = o;
}

// ---- persistent recurrence kernel ------------------------------------------
__global__ __launch_bounds__(kThreads, 2) void lstm_kernel(LstmParams p) {
  // LDS map: [0,128K) per-wave h staging chunks (32 KB each); Red (64 KB)
  // overlaid on [0,64K) — protected by the barrier after phase-H consume.
  // [128K,130K) Hout repack tile. shFC (16 KB) overlaid at 0 post-loop.
  __shared__ __align__(16) char smem[133120];
  v4f* Red = (v4f*)smem;              // [slot = wvp*16+g*4+m][lane]
  u16* Hout = (u16*)(smem + 131072);  // [64 rows][16 units]
  u16* shFC = (u16*)smem;             // 8 rows x 1024 bf16 (post-loop only)

  const int tid = threadIdx.x;
  const int lane = tid & 63;
  const int wv = tid >> 6;           // wave = K-quarter owner AND m-tile owner in combine
  const int blk = blockIdx.x;
  const int mt = blk & 3;            // batch tile 0..3 = barrier group
  const int ut = blk >> 2;           // 0..63: 16 hidden units (x4 gates)

  const int mloc = lane & 15;
  const int q = lane >> 4;
  const int uglob = ut * 16 + mloc;

  unsigned* gflags = p.flags + mt * 256;   // 64 slots, stride 4 u32 (16B)

  float bias[4];
#pragma unroll
  for (int g = 0; g < 4; ++g) bias[g] = p.bi[g][uglob] + p.bh[g][uglob];

  float creg[4] = {0.f, 0.f, 0.f, 0.f};    // cell state for rows mt*64+wv*16+q*4+r

  // ---- h-weights resident in registers (128 VGPRs); x-weights streamed ----
  v8bf bhh[QH][4];
#pragma unroll
  for (int g = 0; g < 4; ++g)
#pragma unroll
    for (int i = 0; i < QH; ++i)
      bhh[i][g] = *((const v8bf*)p.wht[g] + ((size_t)(ut * KSH + wv * QH + i) * 64 + lane));

  for (int t = 0; t < kT; ++t) {
    v4f acc[4][4];    // [m-tile][gate] partials for this wave's K-quarter
#pragma unroll
    for (int m = 0; m < 4; ++m)
#pragma unroll
      for (int g = 0; g < 4; ++g) acc[m][g] = (v4f){0.f, 0.f, 0.f, 0.f};

    // ---- phase X: x-part MFMAs, pre-poll (independent of h); wi from L2 ----
    const v8bf* xf = (const v8bf*)p.xt + ((size_t)(t * 4 + mt) * 4 * KSX) * 64;
#pragma unroll
    for (int i = 0; i < QX; ++i) {
      v8bf bxl[4];
#pragma unroll
      for (int g = 0; g < 4; ++g)
        bxl[g] = *((const v8bf*)p.wit[g] + ((size_t)(ut * KSX + wv * QX + i) * 64 + lane));
#pragma unroll
      for (int mi = 0; mi < 4; ++mi) {
        const v8bf a = xf[(size_t)(mi * KSX + wv * QX + i) * 64 + lane];
#pragma unroll
        for (int g = 0; g < 4; ++g)
          acc[mi][g] = __builtin_amdgcn_mfma_f32_16x16x32_bf16(a, bxl[g], acc[mi][g], 0, 0, 0);
      }
    }

    if (t > 0) {
      if (wv == 0) {   // group barrier: 64 lanes poll 64 padded flags
        while (true) {
          unsigned v = __hip_atomic_load(&gflags[lane * 4], __ATOMIC_RELAXED,
                                         __HIP_MEMORY_SCOPE_AGENT);
          if (__ballot(v >= (unsigned)t) == ~0ull) break;
          __builtin_amdgcn_s_sleep(1);
        }
      }
      __syncthreads();   // release all waves past the barrier

      // ---- phase H: stage this wave's 32 KB h chunk via coherent
      //      global_load_lds (LLC-serviced), then ds_read + MFMA.
      const char* hread = (const char*)(p.hbuf + (size_t)(t & 1) * kB * kH);
      char* myHs = smem + wv * 32768;
#pragma unroll
      for (int mi = 0; mi < 4; ++mi)
#pragma unroll
        for (int i = 0; i < QH; ++i) {
          const size_t sl = (size_t)((mt * 4 + mi) * KSH + wv * QH + i);
          ld16c(hread + sl * 1024 + lane * 16, myHs + (mi * QH + i) * 1024);
        }

      // r7 BUG FIX: global_load_lds results are NOT visible to ds_read until
      // vmcnt drains; the compiler does not track this dependency. This
      // barrier emits s_waitcnt vmcnt(0) + s_barrier (r2-r4-proven mechanism).
      __syncthreads();

#pragma unroll
      for (int mi = 0; mi < 4; ++mi)
#pragma unroll
        for (int i = 0; i < QH; ++i) {
          const v8bf a = *(const v8bf*)(myHs + (mi * QH + i) * 1024 + lane * 16);
#pragma unroll
          for (int g = 0; g < 4; ++g)
            acc[mi][g] = __builtin_amdgcn_mfma_f32_16x16x32_bf16(a, bhh[i][g], acc[mi][g], 0, 0, 0);
        }
    }

    __syncthreads();   // all phase-H ds_reads done: Red overlay now safe

    // ---- cross-wave K-reduction through LDS ----
#pragma unroll
    for (int m = 0; m < 4; ++m)
#pragma unroll
      for (int g = 0; g < 4; ++g)
        Red[(wv * 16 + g * 4 + m) * 64 + lane] = acc[m][g];
    __syncthreads();

    // combine: this thread owns rows mt*64+wv*16+q*4+{0..3}, unit uglob
    v4f gacc[4];
#pragma unroll
    for (int g = 0; g < 4; ++g) {
      v4f s = Red[(0 * 16 + g * 4 + wv) * 64 + lane];
#pragma unroll
      for (int wvp = 1; wvp < 4; ++wvp) {
        const v4f z = Red[(wvp * 16 + g * 4 + wv) * 64 + lane];
#pragma unroll
        for (int r = 0; r < 4; ++r) s[r] += z[r];
      }
      gacc[g] = s;
    }

    // gates -> h; repack through Hout so global stores are coalesced 8B
#pragma unroll
    for (int r = 0; r < 4; ++r) {
      const float iv = sigm(gacc[0][r] + bias[0]);
      const float fv = sigm(gacc[1][r] + bias[1]);
      const float gv = tanh_f(gacc[2][r] + bias[2]);
      const float ov = sigm(gacc[3][r] + bias[3]);
      creg[r] = fv * creg[r] + iv * gv;
      const float hv = ov * tanh_f(creg[r]);
      Hout[(wv * 16 + q * 4 + r) * 16 + mloc] = f2b(hv);
    }
    __syncthreads();   // Hout complete

    // coalesced write-through: frag layout [slice][L][j]; this block's h =
    // 8 contiguous 256B runs: (mi 0..3) x (hbit 0..1) at slice byte off hi*256
    {
      u16* hw = p.hbuf + (size_t)((t + 1) & 1) * kB * kH;
      const int c = tid >> 5;          // chunk 0..7
      const int mi_s = c >> 1;
      const int hbit = c & 1;
      const int hi = (ut * 2 + hbit) & 3;
      const int row16 = (tid & 31) >> 1;
      const int j0 = (tid & 1) * 4;
      const u64 v = *(const u64*)&Hout[(mi_s * 16 + row16) * 16 + hbit * 8 + j0];
      u64* dst = (u64*)((char*)hw + ((size_t)((mt * 4 + mi_s) * KSH + (ut >> 1)) * 1024)
                        + hi * 256 + row16 * 16 + j0 * 2);
      __hip_atomic_store(dst, v, __ATOMIC_RELAXED, __HIP_MEMORY_SCOPE_AGENT);
    }

    __syncthreads();   // drains vmcnt: all h stores acked at LLC (r4-validated)
    if (tid == 0)
      __hip_atomic_fetch_add(&gflags[ut * 4], 1u, __ATOMIC_RELAXED,
                             __HIP_MEMORY_SCOPE_AGENT);
  }

  // ---- FC + log_softmax: blocks 0..31, 8 rows x 32 cols. h_last in buf 0 ----
  if (blk < 32) {
    const int gg = blk >> 3;   // mt of rows blk*8..+8
    if (wv == 0) {
      while (true) {
        unsigned v = __hip_atomic_load(&p.flags[gg * 256 + lane * 4], __ATOMIC_RELAXED,
                                       __HIP_MEMORY_SCOPE_AGENT);
        if (__ballot(v >= (unsigned)kT) == ~0ull) break;
        __builtin_amdgcn_s_sleep(1);
      }
    }
    __syncthreads();
    // stage 8 rows from frag-layout h into shFC[row][u] (small, once)
    {
      const int mi = (blk >> 1) & 3;
      const int ks2 = tid >> 3;        // 0..31
      const int ug = (tid >> 1) & 3;   // unit 8-group
      const int rh = tid & 1;          // row half
      u64* hf = (u64*)p.hbuf;          // buffer 0 (kT even)
#pragma unroll
      for (int rr = 0; rr < 4; ++rr) {
        const int row_l = rh * 4 + rr;
        const int r16 = (blk & 1) * 8 + row_l;
        const int L = r16 | (ug << 4);
        const size_t fi = ((size_t)((gg * 4 + mi) * KSH + ks2) * 64 + L) * 2;
        const u64 a = __hip_atomic_load(hf + fi, __ATOMIC_RELAXED, __HIP_MEMORY_SCOPE_AGENT);
        const u64 b = __hip_atomic_load(hf + fi + 1, __ATOMIC_RELAXED, __HIP_MEMORY_SCOPE_AGENT);
        u64* d = (u64*)&shFC[row_l * kH + ks2 * 32 + ug * 8];
        d[0] = a; d[1] = b;
      }
    }
    __syncthreads();
    const int row = tid >> 5;
    const int col = tid & 31;
    const u16* hr = &shFC[row * kH];
    const float* wr = p.wfc + (size_t)col * kH;
    float s = 0.f;
    for (int k = 0; k < kH; k += 4) {
      const float4 w4 = *(const float4*)(wr + k);
      s += b2f(hr[k]) * w4.x + b2f(hr[k + 1]) * w4.y +
           b2f(hr[k + 2]) * w4.z + b2f(hr[k + 3]) * w4.w;
    }
    float mx = s;
#pragma unroll
    for (int off = 16; off; off >>= 1) mx = fmaxf(mx, __shfl_xor(mx, off, 32));
    const float ex = __expf(s - mx);
    float se = ex;
#pragma unroll
    for (int off = 16; off; off >>= 1) se += __shfl_xor(se, off, 32);
    p.out[(blk * 8 + row) * kO + col] = s - mx - __logf(se);
  }
}

extern "C" void kernel_launch(void* const* d_in, const int* in_sizes, int n_in,
                              void* d_out, int out_size, void* d_ws, size_t ws_size,
                              hipStream_t stream) {
  (void)in_sizes; (void)n_in; (void)out_size; (void)ws_size;
  char* ws = (char*)d_ws;

  u16* xt = (u16*)(ws + OFF_XT);
  u16 *wit[4], *wht[4];
  for (int g = 0; g < 4; ++g) {
    wit[g] = (u16*)(ws + OFF_WIT + (size_t)g * SZ_WIT);
    wht[g] = (u16*)(ws + OFF_WHT + (size_t)g * SZ_WHT);
  }

  // dict order: x, (w_ii,w_hi,b_ii,b_hi), (w_if,w_hf,b_if,b_hf),
  //             (w_io,w_ho,b_io,b_ho), (w_ic,w_hc,b_ic,b_hc), w_fc
  // gate order: 0=i, 1=f, 2=g(candidate), 3=o
  const int gsrc[4] = {1, 5, 13, 9};

  hipMemsetAsync(d_ws, 0, 8192, stream);   // zero barrier flags

  cvt_x_tile<<<8192, 256, 0, stream>>>((const float*)d_in[0], xt);
  for (int g = 0; g < 4; ++g) {
    cvt_w_tile<<<256, 256, 0, stream>>>((const float*)d_in[gsrc[g]], wit[g], kI, 4);
    cvt_w_tile<<<512, 256, 0, stream>>>((const float*)d_in[gsrc[g] + 1], wht[g], kH, 5);
  }

  LstmParams p;
  p.xt = xt;
  for (int g = 0; g < 4; ++g) {
    p.wit[g] = wit[g];
    p.wht[g] = wht[g];
    p.bi[g] = (const float*)d_in[gsrc[g] + 2];
    p.bh[g] = (const float*)d_in[gsrc[g] + 3];
  }
  p.wfc = (const float*)d_in[17];
  p.out = (float*)d_out;
  p.flags = (unsigned*)(ws + OFF_FLG);
  p.hbuf = (u16*)(ws + OFF_H);

  void* args[] = {&p};
  hipError_t e = hipLaunchCooperativeKernel((void*)lstm_kernel, dim3(kBlocks),
                                            dim3(kThreads), args, 0, stream);
  if (e != hipSuccess) {
    // Never fail silently (r5 lesson). At this resource envelope >=1 block/CU
    // fits, so a 256-block plain launch co-schedules all blocks safely.
    (void)hipGetLastError();   // clear sticky error
    lstm_kernel<<<dim3(kBlocks), dim3(kThreads), 0, stream>>>(p);
  }
}